// Round 6
// baseline (8780.485 us; speedup 1.0000x reference)
//
#include <hip/hip_runtime.h>

typedef unsigned int u32;
typedef unsigned short u16;
typedef _Float16 half2_t __attribute__((ext_vector_type(2)));

#define TM 94          // T_MOD
#define NB 2           // batches per decoder block
#define DEC_NT 512

// ---------- helpers ----------
__device__ __forceinline__ float bf2f(u16 v){ return __builtin_bit_cast(float, ((u32)v)<<16); }
__device__ __forceinline__ float bflo(u32 v){ return __builtin_bit_cast(float, v<<16); }
__device__ __forceinline__ float bfhi(u32 v){ return __builtin_bit_cast(float, v & 0xffff0000u); }
__device__ __forceinline__ u32 packh2(float a, float b){ half2_t h; h.x=(_Float16)a; h.y=(_Float16)b; return __builtin_bit_cast(u32,h); }
__device__ __forceinline__ float fdot2(u32 a, u32 b, float c){
  return __builtin_amdgcn_fdot2(__builtin_bit_cast(half2_t,a), __builtin_bit_cast(half2_t,b), c, false);
}
__device__ __forceinline__ float h2lo(u32 v){ return (float)__builtin_bit_cast(half2_t,v).x; }
__device__ __forceinline__ float h2hi(u32 v){ return (float)__builtin_bit_cast(half2_t,v).y; }
__device__ __forceinline__ float fast_rcp(float x){ return __builtin_amdgcn_rcpf(x); }
__device__ __forceinline__ float sigmoid_f(float x){ return fast_rcp(1.f + __expf(-x)); }
__device__ __forceinline__ float tanh_f(float x){ float e=__expf(2.f*x); return 1.f - 2.f*fast_rcp(e+1.f); }

// ---------- kernel 0: pack weights, K-transposed coalesced layouts ----------
// Wg2[j][512] uint4, j=0..28: j<13 -> wih row g u32-cols 4j+s (u<50 else 0);
//                             j>=13 -> whh row g u32-cols 4(j-13)+s.
// Wd2[s][400] uint4, s=0..7: thread t=(m*4+part): chunk ii=(s+part)&7, u32 cols part*32+ii*4+k.
__global__ __launch_bounds__(256)
void prep_kernel(const float* __restrict__ wih, const float* __restrict__ whh,
                 const float* __restrict__ Wd,
                 uint4* __restrict__ Wg2, uint4* __restrict__ Wd2)
{
  int idx = blockIdx.x*256 + threadIdx.x;
  if (idx < 14848){
    int j = idx >> 9;
    int g = idx & 511;
    u32 r[4];
    #pragma unroll
    for (int s=0;s<4;s++){
      u32 v = 0u;
      if (j < 13){
        int u = 4*j + s;
        if (u < 50) v = packh2(wih[g*100+2*u], wih[g*100+2*u+1]);
      } else {
        int u = 4*(j-13) + s;
        v = packh2(whh[g*128+2*u], whh[g*128+2*u+1]);
      }
      r[s]=v;
    }
    Wg2[idx] = make_uint4(r[0],r[1],r[2],r[3]);
  } else if (idx < 18048){
    int id2 = idx - 14848;
    int s = id2 / 400;
    int t = id2 - s*400;
    int m = t >> 2, part = t & 3;
    int ii = (s + part) & 7;
    int base = part*32 + ii*4;
    u32 r[4];
    #pragma unroll
    for (int k=0;k<4;k++){
      int u = base + k;
      r[k] = packh2(Wd[m*256 + 2*u], Wd[m*256 + 2*u + 1]);
    }
    Wd2[id2] = make_uint4(r[0],r[1],r[2],r[3]);
  }
}

// ---------- kernel 1: conv + relu -> H (bf16), 256 threads (2 chunks/block) ----------
__global__ __launch_bounds__(256)
void conv_kernel(const float* __restrict__ enc, const float* __restrict__ cw,
                 const float* __restrict__ cb, u16* __restrict__ Hb)
{
  __shared__ float sE[8100];
  const int tid = threadIdx.x;
  const int b = blockIdx.y;
  const float* ep = enc + (size_t)b*8100;
  for (int i=tid;i<8100;i+=256) sE[i]=ep[i];
  __syncthreads();
  const int sub = tid>>7;
  const int t = tid&127;
  if (t >= TM) return;
  const int chunk = blockIdx.x*2 + sub;   // wave-uniform
  const int mo = chunk*10;
  const float* wb = cw + mo*567;          // wave-uniform -> scalar loads
  float acc[10];
  #pragma unroll
  for (int k=0;k<10;k++) acc[k]=cb[mo+k];
  const float* e = sE + t*81;
  #pragma unroll 3
  for (int j=0;j<567;j++){
    float ev = e[j];
    #pragma unroll
    for (int k=0;k<10;k++) acc[k] += ev*wb[k*567+j];
  }
  u32* out = (u32*)Hb + ((size_t)b*9400 + t*100 + mo)/2;
  #pragma unroll
  for (int k=0;k<5;k++){
    u32 lo = __builtin_bit_cast(u32, fmaxf(acc[2*k],0.f));
    u32 hi = __builtin_bit_cast(u32, fmaxf(acc[2*k+1],0.f));
    lo = (lo + 0x7fffu + ((lo>>16)&1u))>>16;
    hi = (hi + 0x7fffu + ((hi>>16)&1u))>>16;
    out[k] = lo | (hi<<16);
  }
}

// ---------- kernel 2: decoder, NB=2, 512 threads, 2 blocks/CU ----------
// LDS layout (bytes):
//   0      sHt   f16 [2][100][96]  H transposed            38400
//   38400  sE    f16 [2][94][100]  exp(2*clamp(HU,±4))     37600
//   76000  sq    f16 [2][256] = [d|s]                       1024
//   77024  sz    f16 [2][256] = [c(100)pad|d(128)]          1024
//   78048  svd   f32 [100]                                   400
//   78448  union: sa f32[2][100]@0 | sbeta f32[2][96]@800 |
//                 sbh2 u32[2][48]@1568 | sg16 f16[2][512]@0  2048
#define OFF_E   38400
#define OFF_Q   76000
#define OFF_Z   77024
#define OFF_VD  78048
#define OFF_U   78448
#define DEC_LDS 80496

__global__ __launch_bounds__(DEC_NT)
void decoder_kernel(const u16* __restrict__ Hb, const uint4* __restrict__ Wd2,
                    const float* __restrict__ Ud, const float* __restrict__ vd,
                    const uint4* __restrict__ Wg2,
                    const float* __restrict__ bih, const float* __restrict__ bhh,
                    float* __restrict__ dT, float* __restrict__ cLast)
{
  extern __shared__ char smem[];
  _Float16* sHt  = (_Float16*)smem;
  _Float16* sE16 = (_Float16*)(smem + OFF_E);
  u32*      sq32 = (u32*)(smem + OFF_Q);
  _Float16* sq16 = (_Float16*)(smem + OFF_Q);
  u32*      sz32 = (u32*)(smem + OFF_Z);
  _Float16* sz16 = (_Float16*)(smem + OFF_Z);
  float*    svd  = (float*)(smem + OFF_VD);
  float*    sa   = (float*)(smem + OFF_U);
  float*    sbeta= (float*)(smem + OFF_U + 800);
  u32*      sbh2 = (u32*)(smem + OFF_U + 1568);
  _Float16* sg16 = (_Float16*)(smem + OFF_U);

  const int tid = threadIdx.x;
  const int b0 = blockIdx.x * NB;

  // ---- stage H transposed -> f16 [bi][m][96]
  {
    const u32* src = (const u32*)(Hb + (size_t)b0*9400);
    for (int i=tid;i<9400;i+=DEC_NT){
      int bi = i/4700; int r = i - bi*4700;
      int t = r/50, mq = r - t*50;
      u32 h = src[i];
      int base = bi*9600 + (2*mq)*96 + t;
      sHt[base]    = (_Float16)bflo(h);
      sHt[base+96] = (_Float16)bfhi(h);
    }
  }
  // zero t-pad (t=94,95)
  for (int i=tid;i<200;i+=DEC_NT){
    int bi=i/100, m=i-bi*100;
    *((u32*)(sHt + bi*9600 + m*96 + 94)) = 0u;
  }
  if (tid < 100) svd[tid] = vd[tid];
  for (int i=tid;i<256;i+=DEC_NT){ sq32[i]=0u; sz32[i]=0u; }
  __syncthreads();

  // ---- E_hu = exp(2*clamp(HU,-4,4)) as f16 [bi][t][100]
  for (int idx=tid; idx<4700; idx+=DEC_NT){
    int kq = idx/188; int r = idx - kq*188;
    int bi = r/94, t = r - bi*94;
    const _Float16* hcol = sHt + bi*9600 + t;
    const float* ud0 = Ud + (kq*4+0)*100;
    const float* ud1 = Ud + (kq*4+1)*100;
    const float* ud2 = Ud + (kq*4+2)*100;
    const float* ud3 = Ud + (kq*4+3)*100;
    float c0=0.f,c1=0.f,c2=0.f,c3=0.f;
    #pragma unroll 5
    for (int mq=0; mq<25; mq++){
      float h0 = (float)hcol[(4*mq+0)*96];
      float h1 = (float)hcol[(4*mq+1)*96];
      float h2 = (float)hcol[(4*mq+2)*96];
      float h3 = (float)hcol[(4*mq+3)*96];
      float4 u0 = *(const float4*)(ud0 + mq*4);
      float4 u1 = *(const float4*)(ud1 + mq*4);
      float4 u2 = *(const float4*)(ud2 + mq*4);
      float4 u3 = *(const float4*)(ud3 + mq*4);
      c0 += h0*u0.x + h1*u0.y + h2*u0.z + h3*u0.w;
      c1 += h0*u1.x + h1*u1.y + h2*u1.z + h3*u1.w;
      c2 += h0*u2.x + h1*u2.y + h2*u2.z + h3*u2.w;
      c3 += h0*u3.x + h1*u3.y + h2*u3.z + h3*u3.w;
    }
    float e0 = __expf(2.f*fminf(fmaxf(c0,-4.f),4.f));
    float e1 = __expf(2.f*fminf(fmaxf(c1,-4.f),4.f));
    float e2 = __expf(2.f*fminf(fmaxf(c2,-4.f),4.f));
    float e3 = __expf(2.f*fminf(fmaxf(c3,-4.f),4.f));
    u32* dst = (u32*)sE16 + bi*4700 + t*50 + kq*2;
    dst[0] = packh2(e0,e1);
    dst[1] = packh2(e2,e3);
  }
  __syncthreads();

  const int mw = tid>>2, part = tid&3;
  const float biasg = bih[tid] + bhh[tid];
  float s_reg = 0.f;                 // LSTM cell state for (bi,p)=(tid>>7,tid&127), tid<256

  #pragma unroll 1
  for (int step=0; step<TM; step++){
    // P1: a[bi][m] = q[bi].Wd[m]; Wd streamed from L2; sa <- e^{2*clamp(a)}
    if (mw < 100){
      const uint4* wp = Wd2 + tid;
      uint4 wA = wp[0];
      uint4 wB = wp[400];
      float a0=0.f, a1=0.f;
      #pragma unroll
      for (int s=0;s<8;s++){
        uint4 w = wA; wA = wB;
        if (s<6) wB = wp[(s+2)*400];
        int ii = (s+part)&7;
        const int qoff = part*32 + ii*4;
        uint4 qa = *(const uint4*)(sq32 + qoff);
        uint4 qb = *(const uint4*)(sq32 + 128 + qoff);
        a0 = fdot2(w.x,qa.x,a0); a0 = fdot2(w.y,qa.y,a0);
        a0 = fdot2(w.z,qa.z,a0); a0 = fdot2(w.w,qa.w,a0);
        a1 = fdot2(w.x,qb.x,a1); a1 = fdot2(w.y,qb.y,a1);
        a1 = fdot2(w.z,qb.z,a1); a1 = fdot2(w.w,qb.w,a1);
      }
      a0 += __shfl_xor(a0,1); a0 += __shfl_xor(a0,2);
      a1 += __shfl_xor(a1,1); a1 += __shfl_xor(a1,2);
      if (part==0){
        sa[mw]     = __expf(2.f*fminf(fmaxf(a0,-8.f),8.f));
        sa[100+mw] = __expf(2.f*fminf(fmaxf(a1,-8.f),8.f));
      }
    }
    __syncthreads();
    // P2: score[bi][t] ∝ -2*sum_m vd[m]/(1 + e2a[m]*E_hu[t][m])  (softmax shift-invariant)
    if (tid < 376){
      int row = tid>>1, th = tid&1;
      int bi = row/94, t = row - bi*94;
      const uint2* eh = (const uint2*)((const u32*)sE16 + bi*4700 + t*50 + th*24);
      const float4* ap = (const float4*)(sa + bi*100 + th*48);
      const float4* vp = (const float4*)(svd + th*48);
      float acc = 0.f;
      #pragma unroll
      for (int c=0;c<12;c++){
        uint2 e2 = eh[c];
        float4 av = ap[c], vv = vp[c];
        float r0 = fast_rcp(1.f + av.x*h2lo(e2.x));
        float r1 = fast_rcp(1.f + av.y*h2hi(e2.x));
        float r2 = fast_rcp(1.f + av.z*h2lo(e2.y));
        float r3 = fast_rcp(1.f + av.w*h2hi(e2.y));
        acc = fmaf(vv.x,r0,acc); acc = fmaf(vv.y,r1,acc);
        acc = fmaf(vv.z,r2,acc); acc = fmaf(vv.w,r3,acc);
      }
      if (th){
        uint2 e2 = eh[12];
        float4 av = ap[12], vv = vp[12];
        float r0 = fast_rcp(1.f + av.x*h2lo(e2.x));
        float r1 = fast_rcp(1.f + av.y*h2hi(e2.x));
        float r2 = fast_rcp(1.f + av.z*h2lo(e2.y));
        float r3 = fast_rcp(1.f + av.w*h2hi(e2.y));
        acc = fmaf(vv.x,r0,acc); acc = fmaf(vv.y,r1,acc);
        acc = fmaf(vv.z,r2,acc); acc = fmaf(vv.w,r3,acc);
      }
      acc += __shfl_xor(acc,1);
      if (!th) sbeta[bi*96+t] = -2.f*acc;
    }
    __syncthreads();
    // P3: softmax over t (one wave per batch) + pack beta into h2 pairs
    if (tid < 128){
      int bi = tid>>6, lane = tid&63;
      float s0 = sbeta[bi*96+lane];
      float s1 = (lane<30)? sbeta[bi*96+64+lane] : -1e30f;
      float mx = fmaxf(s0,s1);
      #pragma unroll
      for (int o=32;o>=1;o>>=1) mx = fmaxf(mx, __shfl_xor(mx,o));
      float e0 = __expf(s0-mx);
      float e1 = (lane<30)? __expf(s1-mx) : 0.f;
      float sm = e0+e1;
      #pragma unroll
      for (int o=32;o>=1;o>>=1) sm += __shfl_xor(sm,o);
      float rs = fast_rcp(sm);
      float b0v = e0*rs;
      float b1v = (lane<30)? e1*rs : 0.f;
      float b0p = __shfl_xor(b0v,1);
      float b1p = __shfl_xor(b1v,1);
      if ((lane&1)==0){
        sbh2[bi*48 + (lane>>1)] = packh2(b0v, b0p);
        if (lane < 32) sbh2[bi*48 + 32 + (lane>>1)] = packh2(b1v, b1p);
      }
    }
    __syncthreads();
    // P4: c[bi][m] = beta . H^T[m]  (h2-packed fdot2, one thread per (bi,m))
    if (tid < 256){
      int bi = tid>>7, m = tid&127;
      if (m < 100){
        const uint4* hp = (const uint4*)(sHt + bi*9600 + m*96);
        const uint4* bp = (const uint4*)(sbh2 + bi*48);
        float acc=0.f;
        #pragma unroll
        for (int c=0;c<12;c++){
          uint4 h4 = hp[c];
          uint4 b4 = bp[c];
          acc = fdot2(h4.x,b4.x,acc); acc = fdot2(h4.y,b4.y,acc);
          acc = fdot2(h4.z,b4.z,acc); acc = fdot2(h4.w,b4.w,acc);
        }
        sz16[bi*256+m] = (_Float16)acc;
        if (step==TM-1) cLast[(size_t)(b0+bi)*100+m] = acc;
      }
    }
    __syncthreads();
    // P5: gates[bi][g] = bias + Wg[g].z[bi]; Wg streamed from L2 (depth-4 prefetch);
    //     z reads are wave-uniform -> LDS broadcast
    {
      const int g = tid;
      float accA = biasg, accB = biasg;
      const uint4* wp5 = Wg2 + g;
      uint4 W0 = wp5[0], W1 = wp5[512], W2 = wp5[1024], W3 = wp5[1536];
      #pragma unroll 1
      for (int j=0;j<29;j++){
        uint4 w = W0; W0=W1; W1=W2; W2=W3;
        int jn = j+4; if (jn>28) jn=28;
        W3 = wp5[jn*512];
        int zoff = 4*j + ((j>=13)?12:0);
        uint4 za = *(const uint4*)(sz32 + zoff);
        uint4 zb = *(const uint4*)(sz32 + 128 + zoff);
        accA = fdot2(w.x,za.x,accA); accA = fdot2(w.y,za.y,accA);
        accA = fdot2(w.z,za.z,accA); accA = fdot2(w.w,za.w,accA);
        accB = fdot2(w.x,zb.x,accB); accB = fdot2(w.y,zb.y,accB);
        accB = fdot2(w.z,zb.z,accB); accB = fdot2(w.w,zb.w,accB);
      }
      sg16[g]     = (_Float16)accA;
      sg16[512+g] = (_Float16)accB;
    }
    __syncthreads();
    // P6: LSTM pointwise (tid<256: 2 bi x 128 p); s in register
    if (tid < 256){
      int bi = tid>>7, p = tid&127;
      float ig = (float)sg16[bi*512+p];
      float fg = (float)sg16[bi*512+128+p];
      float gg = (float)sg16[bi*512+256+p];
      float og = (float)sg16[bi*512+384+p];
      float sn = sigmoid_f(fg)*s_reg + sigmoid_f(ig)*tanh_f(gg);
      float dn = sigmoid_f(og)*tanh_f(sn);
      s_reg = sn;
      sq16[bi*256+p]     = (_Float16)dn;   // q = [d|s]
      sq16[bi*256+128+p] = (_Float16)sn;
      sz16[bi*256+128+p] = (_Float16)dn;   // z = [c|d]
      if (step==TM-1) dT[(size_t)(b0+bi)*128+p]=dn;
    }
    __syncthreads();
  }
}

// ---------- kernel 3: skip GRU, 8 rows/block, 9 steps ----------
__global__ __launch_bounds__(256)
void gru_kernel(const u16* __restrict__ Hb, const float* __restrict__ wih,
                const float* __restrict__ whh, const float* __restrict__ bihp,
                const float* __restrict__ bhhp, float* __restrict__ hskip)
{
  __shared__ float sWih[96][101];
  __shared__ float sWhh[96][33];
  __shared__ float sxt[8][100];
  __shared__ float sh[8][33];
  const int tid = threadIdx.x;
  for (int i=tid;i<9600;i+=256){ sWih[i/100][i%100]=wih[i]; }
  for (int i=tid;i<3072;i+=256){ sWhh[i>>5][i&31]=whh[i]; }
  const int r = tid>>5, j = tid&31;
  const int rowg = blockIdx.x*8 + r;
  const int b = rowg/10, sk = rowg - b*10;
  const float b_r = bihp[j], b_z = bihp[32+j], b_n = bihp[64+j];
  const float hb_r = bhhp[j], hb_z = bhhp[32+j], hb_n = bhhp[64+j];
  sh[r][j]=0.f;
  float h = 0.f;
  __syncthreads();
  for (int pt=0; pt<9; pt++){
    for (int i=tid;i<800;i+=256){
      int rr=i/100, m=i-rr*100;
      int rg = blockIdx.x*8+rr; int bb=rg/10, ss=rg-bb*10;
      sxt[rr][m] = bf2f(Hb[(size_t)bb*9400 + (size_t)(4+pt*10+ss)*100 + m]);
    }
    __syncthreads();
    float gi_r=b_r, gi_z=b_z, gi_n=b_n, gh_r=hb_r, gh_z=hb_z, gh_n=hb_n;
    #pragma unroll 4
    for (int m=0;m<100;m++){
      float x = sxt[r][m];
      gi_r += sWih[j][m]*x; gi_z += sWih[32+j][m]*x; gi_n += sWih[64+j][m]*x;
    }
    #pragma unroll
    for (int k=0;k<32;k++){
      float hp = sh[r][k];
      gh_r += sWhh[j][k]*hp; gh_z += sWhh[32+j][k]*hp; gh_n += sWhh[64+j][k]*hp;
    }
    float rg_ = sigmoid_f(gi_r+gh_r);
    float z  = sigmoid_f(gi_z+gh_z);
    float n  = tanh_f(gi_n + rg_*gh_n);
    h = (1.f-z)*n + z*h;
    __syncthreads();
    sh[r][j]=h;
    __syncthreads();
  }
  hskip[(size_t)b*320 + sk*32 + j] = h;
}

// ---------- kernel 4: output MLP head, 32 batches/block, w1 tiled via LDS ----------
#define OUT_NB 32
#define OUT_LDS ((OUT_NB*552 + 8*552)*4)   // 88320 bytes

__global__ __launch_bounds__(256)
void out_kernel(const float* __restrict__ dT, const float* __restrict__ cLast,
                const float* __restrict__ hskip, const float* __restrict__ w1,
                const float* __restrict__ b1, const float* __restrict__ w2,
                const float* __restrict__ b2, float* __restrict__ outp)
{
  extern __shared__ float osm[];
  float* sf = osm;                 // [32][552]
  float* sw = osm + OUT_NB*552;    // [8][552]
  const int tid = threadIdx.x;
  const int b0 = blockIdx.x*OUT_NB;
  for (int i=tid;i<OUT_NB*548;i+=256){
    int bl = i/548, k = i - 548*bl; int b = b0+bl;
    float v;
    if (k<128) v = dT[(size_t)b*128+k];
    else if (k<228) v = cLast[(size_t)b*100+(k-128)];
    else v = hskip[(size_t)b*320+(k-228)];
    sf[bl*552+k]=v;
  }
  const int bl = tid>>3, j = tid&7;
  float outv = 0.f;
  for (int jt=0; jt<128; jt+=8){
    __syncthreads();
    for (int i=tid;i<8*548;i+=256){
      int rr=i/548, c=i-548*rr;
      sw[rr*552+c] = w1[(size_t)jt*548 + i];
    }
    __syncthreads();
    float acc = b1[jt+j];
    const float* fr = sf + bl*552;
    const float* wr = sw + j*552;
    #pragma unroll 4
    for (int k=0;k<548;k++) acc += fr[k]*wr[k];
    outv += fmaxf(acc,0.f)*w2[jt+j];
  }
  outv += __shfl_xor(outv,1);
  outv += __shfl_xor(outv,2);
  outv += __shfl_xor(outv,4);
  if (j==0) outp[b0+bl] = outv + b2[0];
}

// ---------- launcher ----------
extern "C" void kernel_launch(void* const* d_in, const int* in_sizes, int n_in,
                              void* d_out, int out_size, void* d_ws, size_t ws_size,
                              hipStream_t stream)
{
  const float* enc      = (const float*)d_in[0];
  const float* conv_w   = (const float*)d_in[1];
  const float* conv_b   = (const float*)d_in[2];
  const float* Wd       = (const float*)d_in[3];
  const float* Ud       = (const float*)d_in[4];
  const float* vd       = (const float*)d_in[5];
  const float* lstm_wih = (const float*)d_in[6];
  const float* lstm_whh = (const float*)d_in[7];
  const float* lstm_bih = (const float*)d_in[8];
  const float* lstm_bhh = (const float*)d_in[9];
  const float* gru_wih  = (const float*)d_in[10];
  const float* gru_whh  = (const float*)d_in[11];
  const float* gru_bih  = (const float*)d_in[12];
  const float* gru_bhh  = (const float*)d_in[13];
  const float* out1_w   = (const float*)d_in[14];
  const float* out1_b   = (const float*)d_in[15];
  const float* out2_w   = (const float*)d_in[16];
  const float* out2_b   = (const float*)d_in[17];

  char* ws = (char*)d_ws;
  u16*   Hb    = (u16*)ws;                         // 4096*9400*2 = 77,004,800 B
  float* dT    = (float*)(ws + 77004800);          // 2,097,152 B
  float* cLast = (float*)(ws + 79101952);          // 1,638,400 B
  float* hskip = (float*)(ws + 80740352);          // 5,242,880 B
  // Wg2/Wd2 alias hskip region (dead until gru_kernel, which runs after decoder)
  uint4* Wg2   = (uint4*)(ws + 80740352);          // 14848*16 = 237,568 B
  uint4* Wd2   = (uint4*)(ws + 80740352 + 237568); // 3200*16  =  51,200 B

  prep_kernel<<<71, 256, 0, stream>>>(lstm_wih, lstm_whh, Wd, Wg2, Wd2);

  conv_kernel<<<dim3(5,4096,1), 256, 0, stream>>>(enc, conv_w, conv_b, Hb);

  (void)hipFuncSetAttribute((const void*)decoder_kernel,
                            hipFuncAttributeMaxDynamicSharedMemorySize, DEC_LDS);
  decoder_kernel<<<4096/NB, DEC_NT, DEC_LDS, stream>>>(Hb, Wd2, Ud, vd, Wg2,
                                                       lstm_bih, lstm_bhh,
                                                       dT, cLast);

  gru_kernel<<<5120, 256, 0, stream>>>(Hb, gru_wih, gru_whh, gru_bih, gru_bhh, hskip);

  (void)hipFuncSetAttribute((const void*)out_kernel,
                            hipFuncAttributeMaxDynamicSharedMemorySize, OUT_LDS);
  out_kernel<<<4096/OUT_NB, 256, OUT_LDS, stream>>>(dT, cLast, hskip, out1_w, out1_b,
                                                    out2_w, out2_b, (float*)d_out);
}